// Round 2
// baseline (111.429 us; speedup 1.0000x reference)
//
#include <hip/hip_runtime.h>

// Batched scalar neural-ODE, RK4, 99 steps, tiny 2->4->1 LeakyReLU MLP.
// One thread per batch element; one wave (64 threads) per block.
//
// Key change vs R0: the [B,100] fp32 output was stored as per-thread float4
// at 400B stride -> every 16B in a different 64B sector -> L2 write-allocate
// RMW + eviction of partial lines (~8x HBM write traffic). Now each thread
// stages its 100-float trajectory in LDS (identity layout mirroring the
// block's contiguous 25.6KB output region), then the wave does a linear
// LDS->global flush: 64 lanes x 16B = 1KB contiguous full sectors per store.
//
// LeakyReLU folded into the output dot product:
//   leaky(h) = 0.505*h + 0.495*|h|  (slope 0.01)
//   w*leaky(h) = (0.505w)*h + (0.495w)*|h|  -> |h| is a free VOP3 abs modifier.

#define NSTEP 100
#define BLK 64  // one wave per block

__global__ __launch_bounds__(BLK) void rk4_net_kernel(
    const float* __restrict__ x, const float* __restrict__ u,
    const float* __restrict__ W1, const float* __restrict__ b1,
    const float* __restrict__ W2, const float* __restrict__ b2,
    float* __restrict__ out, int B)
{
    const int l = threadIdx.x;                 // lane 0..63
    const int b = blockIdx.x * BLK + l;

    // 64 rows x 25 float4 = block's contiguous 25.6KB output region
    __shared__ float4 stage[BLK * 25];

    // Uniform weights (W1 row-major (2,4): row 0 multiplies s, row 1 multiplies u)
    const float A0 = W1[0], A1 = W1[1], A2 = W1[2], A3 = W1[3];
    const float U0 = W1[4], U1 = W1[5], U2 = W1[6], U3 = W1[7];
    const float w0 = W2[0], w1 = W2[1], w2 = W2[2], w3 = W2[3];
    const float bias2 = b2[0];

    const float uu = u[b];
    float s = x[b];

    // Per-thread hidden-layer constants: C_i = u*W1[1][i] + b1[i]
    const float C0 = fmaf(uu, U0, b1[0]);
    const float C1 = fmaf(uu, U1, b1[1]);
    const float C2 = fmaf(uu, U2, b1[2]);
    const float C3 = fmaf(uu, U3, b1[3]);

    // LeakyReLU folded weights
    const float al = 0.505f, be = 0.495f;
    const float wa0 = al * w0, wa1 = al * w1, wa2 = al * w2, wa3 = al * w3;
    const float wb0 = be * w0, wb1 = be * w1, wb2 = be * w2, wb3 = be * w3;

    auto dyn = [&](float sv) -> float {
        float h0 = fmaf(sv, A0, C0);
        float h1 = fmaf(sv, A1, C1);
        float h2 = fmaf(sv, A2, C2);
        float h3 = fmaf(sv, A3, C3);
        // two independent FMA chains (depth 4) -> ILP 2, |h| via abs modifier
        float p = fmaf(h0, wa0, bias2);
        float q = __builtin_fabsf(h0) * wb0;
        p = fmaf(h1, wa1, p);
        q = fmaf(__builtin_fabsf(h1), wb1, q);
        p = fmaf(h2, wa2, p);
        q = fmaf(__builtin_fabsf(h2), wb2, q);
        p = fmaf(h3, wa3, p);
        q = fmaf(__builtin_fabsf(h3), wb3, q);
        return p + q;
    };

    auto step = [&](float sv) -> float {
        float k1 = dyn(sv);
        float k2 = dyn(fmaf(0.5f, k1, sv));
        float k3 = dyn(fmaf(0.5f, k2, sv));
        float k4 = dyn(sv + k3);
        float sum = fmaf(2.0f, k2, k1);
        sum = fmaf(2.0f, k3, sum);
        sum += k4;
        return fmaf(0.16666667f, sum, sv);  // DT/6
    };

    float4 v;
    v.x = s;                 // t = 0 is the initial state
    s = step(s); v.y = s;
    s = step(s); v.z = s;
    s = step(s); v.w = s;
    stage[l * 25 + 0] = v;

#pragma unroll 1
    for (int c = 1; c < 25; ++c) {
        s = step(s); v.x = s;
        s = step(s); v.y = s;
        s = step(s); v.z = s;
        s = step(s); v.w = s;
        stage[l * 25 + c] = v;
    }

    __syncthreads();  // single wave: compiles to lgkmcnt wait + barrier, cheap

    // Linear flush: LDS flat index == region-local global float4 index.
    // Each instruction: 64 lanes x 16B = 1KB contiguous, full 64B sectors.
    float4* o4 = (float4*)out + (size_t)blockIdx.x * (BLK * 25);
#pragma unroll
    for (int k = 0; k < 25; ++k) {
        o4[k * BLK + l] = stage[k * BLK + l];
    }
}

extern "C" void kernel_launch(void* const* d_in, const int* in_sizes, int n_in,
                              void* d_out, int out_size, void* d_ws, size_t ws_size,
                              hipStream_t stream) {
    const float* x  = (const float*)d_in[0];
    const float* u  = (const float*)d_in[1];
    const float* W1 = (const float*)d_in[2];
    const float* b1 = (const float*)d_in[3];
    const float* W2 = (const float*)d_in[4];
    const float* b2 = (const float*)d_in[5];
    float* out = (float*)d_out;

    const int B = in_sizes[0];
    const int grid = (B + BLK - 1) / BLK;
    hipLaunchKernelGGL(rk4_net_kernel, dim3(grid), dim3(BLK), 0, stream,
                       x, u, W1, b1, W2, b2, out, B);
}

// Round 4
// 103.506 us; speedup vs baseline: 1.0766x; 1.0766x over previous
//
#include <hip/hip_runtime.h>

// Batched scalar neural-ODE, RK4, 99 steps, tiny 2->4->1 LeakyReLU MLP.
// R4 = R3 resubmit (R3 died to a host-side core dump with no validation
// output; kernel audited clean for OOB/alignment — treating as infra flake).
//
// Design: two batch elements per thread (1024 waves = 1/SIMD on all 1024
// SIMDs, per-wave ILP ~4 from two independent integrations) + algebraic fold
// of the MLP's linear part:
//   leaky(h) = 0.505*h + 0.495*|h|
//   dyn(s)   = b2 + sum_i w_i*leaky(h_i),  h_i = A_i*s + C_i
//            = fma(s, P, Q) + sum_i (0.495 w_i)*|h_i|
//   with P = sum_i (0.505 w_i) A_i  (uniform),
//        Q = b2 + sum_i (0.505 w_i) C_i,  C_i = u*W1[1][i] + b1[i] (per-thread).
// |h| is a free VOP3 abs modifier -> dyn = 11 VALU, depth 5.

#define NSTEP 100
#define BLK 256

__global__ __launch_bounds__(BLK) void rk4_net_kernel(
    const float* __restrict__ x, const float* __restrict__ u,
    const float* __restrict__ W1, const float* __restrict__ b1,
    const float* __restrict__ W2, const float* __restrict__ b2,
    float* __restrict__ out, int B)
{
    const int i = blockIdx.x * BLK + threadIdx.x;   // pair index
    if (i >= (B >> 1)) return;

    // Uniform weights (W1 row-major (2,4): row 0 multiplies s, row 1 multiplies u)
    const float A0 = W1[0], A1 = W1[1], A2 = W1[2], A3 = W1[3];
    const float U0 = W1[4], U1 = W1[5], U2 = W1[6], U3 = W1[7];
    const float w0 = W2[0], w1 = W2[1], w2 = W2[2], w3 = W2[3];
    const float bias2 = b2[0];
    const float B0 = b1[0], B1 = b1[1], B2 = b1[2], B3 = b1[3];

    const float al = 0.505f, be = 0.495f;
    const float wa0 = al * w0, wa1 = al * w1, wa2 = al * w2, wa3 = al * w3;
    const float wb0 = be * w0, wb1 = be * w1, wb2 = be * w2, wb3 = be * w3;
    // Linear fold: P = sum wa_i * A_i  (uniform across threads)
    float P = wa0 * A0;
    P = fmaf(wa1, A1, P);
    P = fmaf(wa2, A2, P);
    P = fmaf(wa3, A3, P);

    // Two batch elements per thread: 2i and 2i+1 (coalesced float2 loads)
    const float2 xx = ((const float2*)x)[i];
    const float2 uu = ((const float2*)u)[i];

    // Per-element constants
    const float C00 = fmaf(uu.x, U0, B0), C01 = fmaf(uu.x, U1, B1),
                C02 = fmaf(uu.x, U2, B2), C03 = fmaf(uu.x, U3, B3);
    const float C10 = fmaf(uu.y, U0, B0), C11 = fmaf(uu.y, U1, B1),
                C12 = fmaf(uu.y, U2, B2), C13 = fmaf(uu.y, U3, B3);
    float Q0 = fmaf(wa0, C00, bias2);
    Q0 = fmaf(wa1, C01, Q0); Q0 = fmaf(wa2, C02, Q0); Q0 = fmaf(wa3, C03, Q0);
    float Q1 = fmaf(wa0, C10, bias2);
    Q1 = fmaf(wa1, C11, Q1); Q1 = fmaf(wa2, C12, Q1); Q1 = fmaf(wa3, C13, Q1);

    auto dyn = [&](float s, float c0, float c1, float c2, float c3,
                   float Q) -> float {
        float h0 = fmaf(s, A0, c0);
        float h1 = fmaf(s, A1, c1);
        float h2 = fmaf(s, A2, c2);
        float h3 = fmaf(s, A3, c3);
        float t0 = __builtin_fabsf(h0) * wb0;
        float t1 = __builtin_fabsf(h1) * wb1;
        t0 = fmaf(__builtin_fabsf(h2), wb2, t0);
        t1 = fmaf(__builtin_fabsf(h3), wb3, t1);
        float lin = fmaf(s, P, Q);
        return lin + (t0 + t1);
    };

    auto step = [&](float s, float c0, float c1, float c2, float c3,
                    float Q) -> float {
        float k1 = dyn(s, c0, c1, c2, c3, Q);
        float k2 = dyn(fmaf(0.5f, k1, s), c0, c1, c2, c3, Q);
        float k3 = dyn(fmaf(0.5f, k2, s), c0, c1, c2, c3, Q);
        float k4 = dyn(s + k3, c0, c1, c2, c3, Q);
        float sum = fmaf(2.0f, k2, k1);
        sum = fmaf(2.0f, k3, sum);
        sum += k4;
        return fmaf(0.16666667f, sum, s);  // DT/6
    };

    float s0 = xx.x, s1 = xx.y;

    // Output rows for the two elements; row base (e*400B) is 16B aligned.
    float4* o0 = (float4*)(out + (size_t)(2 * i) * NSTEP);
    float4* o1 = (float4*)(out + (size_t)(2 * i + 1) * NSTEP);

    float4 v0, v1;
    v0.x = s0; v1.x = s1;   // t = 0 is the initial state
    s0 = step(s0, C00, C01, C02, C03, Q0); v0.y = s0;
    s1 = step(s1, C10, C11, C12, C13, Q1); v1.y = s1;
    s0 = step(s0, C00, C01, C02, C03, Q0); v0.z = s0;
    s1 = step(s1, C10, C11, C12, C13, Q1); v1.z = s1;
    s0 = step(s0, C00, C01, C02, C03, Q0); v0.w = s0;
    s1 = step(s1, C10, C11, C12, C13, Q1); v1.w = s1;
    o0[0] = v0;
    o1[0] = v1;

#pragma unroll 1
    for (int c = 1; c < 25; ++c) {
        s0 = step(s0, C00, C01, C02, C03, Q0); v0.x = s0;
        s1 = step(s1, C10, C11, C12, C13, Q1); v1.x = s1;
        s0 = step(s0, C00, C01, C02, C03, Q0); v0.y = s0;
        s1 = step(s1, C10, C11, C12, C13, Q1); v1.y = s1;
        s0 = step(s0, C00, C01, C02, C03, Q0); v0.z = s0;
        s1 = step(s1, C10, C11, C12, C13, Q1); v1.z = s1;
        s0 = step(s0, C00, C01, C02, C03, Q0); v0.w = s0;
        s1 = step(s1, C10, C11, C12, C13, Q1); v1.w = s1;
        o0[c] = v0;
        o1[c] = v1;
    }
}

extern "C" void kernel_launch(void* const* d_in, const int* in_sizes, int n_in,
                              void* d_out, int out_size, void* d_ws, size_t ws_size,
                              hipStream_t stream) {
    const float* x  = (const float*)d_in[0];
    const float* u  = (const float*)d_in[1];
    const float* W1 = (const float*)d_in[2];
    const float* b1 = (const float*)d_in[3];
    const float* W2 = (const float*)d_in[4];
    const float* b2 = (const float*)d_in[5];
    float* out = (float*)d_out;

    const int B = in_sizes[0];
    const int pairs = B >> 1;                       // 65536
    const int grid = (pairs + BLK - 1) / BLK;       // 256 blocks -> 1024 waves
    hipLaunchKernelGGL(rk4_net_kernel, dim3(grid), dim3(BLK), 0, stream,
                       x, u, W1, b1, W2, b2, out, B);
}